// Round 1
// baseline (618.188 us; speedup 1.0000x reference)
//
#include <hip/hip_runtime.h>
#include <hip/hip_bf16.h>
#include <cstdint>
#include <cstddef>

#define N_TOK   32768
#define D_IN    1024
#define D_OUT   1024
#define NE      8

typedef __attribute__((ext_vector_type(4))) float floatx4;
typedef __attribute__((ext_vector_type(8))) short bf16x8;

__device__ __forceinline__ unsigned short f2bf(float f) {
  union { float f; unsigned int u; } v; v.f = f;
  unsigned int u = v.u + 0x7fffu + ((v.u >> 16) & 1u);   // RNE
  return (unsigned short)(u >> 16);
}

// async global->LDS, 16B per lane; LDS dest is wave-uniform base + lane*16
__device__ __forceinline__ void gload_lds16(const void* g, void* l) {
  __builtin_amdgcn_global_load_lds(
      (const __attribute__((address_space(1))) unsigned int*)g,
      (__attribute__((address_space(3))) unsigned int*)l, 16, 0, 0);
}

// ---------------- W fp32 -> bf16 cast ----------------
__global__ __launch_bounds__(256) void cast_w_kernel(const float* __restrict__ W,
                                                     unsigned short* __restrict__ Wb) {
  int i = blockIdx.x * 256 + threadIdx.x;          // float4 index; grid covers exactly
  float4 v = ((const float4*)W)[i];
  ushort4 h;
  h.x = f2bf(v.x); h.y = f2bf(v.y); h.z = f2bf(v.z); h.w = f2bf(v.w);
  ((ushort4*)Wb)[i] = h;
}

// ---------------- gating + x cast + bucket build ----------------
// one wave per token; 64 tokens per block; grid = N_TOK/64
__global__ __launch_bounds__(256) void gate_kernel(
    const float* __restrict__ x,
    const float* __restrict__ Wg,
    const float* __restrict__ bg,
    unsigned short* __restrict__ xb,
    int* __restrict__ counts,
    int* __restrict__ bids,
    float* __restrict__ bw)
{
  __shared__ float wg_lds[NE * D_IN];   // 32 KB
  __shared__ int lcnt[NE];
  __shared__ int basee[NE];
  __shared__ int   tok_e[64][2];
  __shared__ int   tok_s[64][2];
  __shared__ float tok_w[64][2];

  const int tid = threadIdx.x;
  {
    const float4* s = (const float4*)Wg;
    float4* d = (float4*)wg_lds;
    for (int i = tid; i < NE * D_IN / 4; i += 256) d[i] = s[i];
  }
  if (tid < NE) lcnt[tid] = 0;
  __syncthreads();

  const int wave = tid >> 6, lane = tid & 63;
  const float4* x4 = (const float4*)x;
  const float4* w4 = (const float4*)wg_lds;

  for (int t = 0; t < 16; ++t) {
    const int lt = wave * 16 + t;
    const int n  = blockIdx.x * 64 + lt;
    float4 xv[4];
    float acc[NE];
#pragma unroll
    for (int e = 0; e < NE; ++e) acc[e] = 0.f;
#pragma unroll
    for (int j = 0; j < 4; ++j) {
      xv[j] = x4[(size_t)n * 256 + j * 64 + lane];
#pragma unroll
      for (int e = 0; e < NE; ++e) {
        float4 w = w4[e * 256 + j * 64 + lane];
        acc[e] += xv[j].x * w.x + xv[j].y * w.y + xv[j].z * w.z + xv[j].w * w.w;
      }
    }
    // fused x -> bf16 cast (coalesced 8B/lane stores)
#pragma unroll
    for (int j = 0; j < 4; ++j) {
      ushort4 h;
      h.x = f2bf(xv[j].x); h.y = f2bf(xv[j].y);
      h.z = f2bf(xv[j].z); h.w = f2bf(xv[j].w);
      ((ushort4*)xb)[(size_t)n * 256 + j * 64 + lane] = h;
    }
    // wave reduce the 8 partial dots
#pragma unroll
    for (int e = 0; e < NE; ++e)
#pragma unroll
      for (int s = 32; s > 0; s >>= 1)
        acc[e] += __shfl_xor(acc[e], s, 64);

    if (lane == 0) {
      float sc[NE];
#pragma unroll
      for (int e = 0; e < NE; ++e) sc[e] = acc[e] + bg[e];
      float m = sc[0];
#pragma unroll
      for (int e = 1; e < NE; ++e) m = fmaxf(m, sc[e]);
      float p[NE], den = 0.f;
#pragma unroll
      for (int e = 0; e < NE; ++e) { p[e] = __expf(sc[e] - m); den += p[e]; }
      int e1 = 0;
#pragma unroll
      for (int e = 1; e < NE; ++e) if (sc[e] > sc[e1]) e1 = e;   // first-index tie-break
      int e2 = (e1 == 0) ? 1 : 0;
#pragma unroll
      for (int e = 0; e < NE; ++e) if (e != e1 && sc[e] > sc[e2]) e2 = e;
      float inv = 1.f / den;
      tok_e[lt][0] = e1; tok_w[lt][0] = p[e1] * inv; tok_s[lt][0] = atomicAdd(&lcnt[e1], 1);
      tok_e[lt][1] = e2; tok_w[lt][1] = p[e2] * inv; tok_s[lt][1] = atomicAdd(&lcnt[e2], 1);
    }
  }
  __syncthreads();
  if (tid < NE) basee[tid] = atomicAdd(&counts[tid], lcnt[tid]);  // 1 global atomic per expert per block
  __syncthreads();
  if (tid < 128) {
    int lt = tid >> 1, kk = tid & 1;
    int e = tok_e[lt][kk];
    int slot = basee[e] + tok_s[lt][kk];
    bids[e * N_TOK + slot] = blockIdx.x * 64 + lt;
    bw[e * N_TOK + slot]   = tok_w[lt][kk];
  }
}

// ---------------- grouped gathered GEMM, m97 structure ----------------
// grid = NE * 256 (M-tiles) * 8 (N-tiles); block 256 = 4 waves (2x2 of 64x64)
__global__ __launch_bounds__(256) void moe_gemm_kernel(
    const unsigned short* __restrict__ xb,    // [N_TOK, 1024] bf16
    const unsigned short* __restrict__ Wb,    // [8, 1024, 1024] bf16 (K contiguous)
    const float* __restrict__ bias,           // [8, 1024] fp32
    const int* __restrict__ counts,
    const int* __restrict__ bids,
    const float* __restrict__ bw,
    float* __restrict__ out)                  // [N_TOK, 1024] fp32, pre-zeroed
{
  const int bid = blockIdx.x;
  const int e   = bid >> 11;
  const int mt  = (bid >> 3) & 255;
  const int nt  = bid & 7;
  const int cnt = counts[e];
  const int row0 = mt << 7;
  if (row0 >= cnt) return;
  const int rows = min(128, cnt - row0);

  __shared__ alignas(16) unsigned short Ald[128 * 32];  // 8 KB
  __shared__ alignas(16) unsigned short Bld[128 * 32];  // 8 KB
  __shared__ int   ids[128];
  __shared__ float wts[128];

  const int tid = threadIdx.x;
  if (tid < 128) {
    int src = (tid < rows) ? tid : 0;                   // clamp tail rows to a valid id
    ids[tid] = bids[e * N_TOK + row0 + src];
    wts[tid] = (tid < rows) ? bw[e * N_TOK + row0 + tid] : 0.f;
  }
  __syncthreads();

  const int wave = tid >> 6;
  const int lane = tid & 63;
  const int wm = wave >> 1, wn = wave & 1;

  // staging: lane -> (row = seg + lane/4, 16B chunk = lane%4); LDS base wave-uniform
  const int srow = lane >> 2;
  const int koff = (lane & 3) * 8;                      // bf16 elements
  const int seg  = wave * 32;
  const long a_r0 = (long)ids[seg + srow] * D_IN;
  const long a_r1 = (long)ids[seg + 16 + srow] * D_IN;
  const unsigned short* wbe = Wb + (size_t)e * D_OUT * D_IN;
  const long b_r0 = (long)(nt * 128 + seg + srow) * D_IN;
  const long b_r1 = (long)(nt * 128 + seg + 16 + srow) * D_IN;
  unsigned short* aL0 = &Ald[seg * 32];
  unsigned short* aL1 = &Ald[(seg + 16) * 32];
  unsigned short* bL0 = &Bld[seg * 32];
  unsigned short* bL1 = &Bld[(seg + 16) * 32];

  const int m16  = lane & 15;
  const int quad = lane >> 4;

  floatx4 acc[4][4];
#pragma unroll
  for (int i = 0; i < 4; ++i)
#pragma unroll
    for (int j = 0; j < 4; ++j) acc[i][j] = (floatx4){0.f, 0.f, 0.f, 0.f};

  for (int k0 = 0; k0 < D_IN; k0 += 32) {
    gload_lds16(xb + a_r0 + k0 + koff, aL0);
    gload_lds16(xb + a_r1 + k0 + koff, aL1);
    gload_lds16(wbe + b_r0 + k0 + koff, bL0);
    gload_lds16(wbe + b_r1 + k0 + koff, bL1);
    __syncthreads();   // compiler emits vmcnt(0) drain before barrier

    bf16x8 af[4], bf[4];
#pragma unroll
    for (int i = 0; i < 4; ++i)
      af[i] = *(const bf16x8*)&Ald[(wm * 64 + i * 16 + m16) * 32 + quad * 8];
#pragma unroll
    for (int j = 0; j < 4; ++j)
      bf[j] = *(const bf16x8*)&Bld[(wn * 64 + j * 16 + m16) * 32 + quad * 8];
#pragma unroll
    for (int i = 0; i < 4; ++i)
#pragma unroll
      for (int j = 0; j < 4; ++j)
        acc[i][j] = __builtin_amdgcn_mfma_f32_16x16x32_bf16(af[i], bf[j], acc[i][j], 0, 0, 0);
    __syncthreads();
  }

  // epilogue: out[token, col] += w * (acc + bias[col]); C/D map: col=lane&15, row=quad*4+reg
  float bv[4];
  int col[4];
#pragma unroll
  for (int j = 0; j < 4; ++j) {
    col[j] = nt * 128 + wn * 64 + j * 16 + m16;
    bv[j] = bias[e * D_OUT + col[j]];
  }
#pragma unroll
  for (int i = 0; i < 4; ++i) {
#pragma unroll
    for (int r = 0; r < 4; ++r) {
      int rl = wm * 64 + i * 16 + quad * 4 + r;
      if (rl < rows) {
        float w = wts[rl];
        float* orow = out + (size_t)ids[rl] * D_OUT;
#pragma unroll
        for (int j = 0; j < 4; ++j)
          atomicAdd(&orow[col[j]], w * (acc[i][j][r] + bv[j]));
      }
    }
  }
}

extern "C" void kernel_launch(void* const* d_in, const int* in_sizes, int n_in,
                              void* d_out, int out_size, void* d_ws, size_t ws_size,
                              hipStream_t stream) {
  const float* x  = (const float*)d_in[0];
  const float* Wg = (const float*)d_in[1];
  const float* bg = (const float*)d_in[2];
  const float* W  = (const float*)d_in[3];
  const float* b  = (const float*)d_in[4];
  float* out = (float*)d_out;

  // workspace layout (all 4 KB aligned): counts | bids(1MB) | bw(1MB) | xb(64MB) | Wb(16MB)
  char* ws = (char*)d_ws;
  int*   counts = (int*)ws;
  int*   bids   = (int*)(ws + 4096);
  float* bw     = (float*)(ws + 4096 + (size_t)NE * N_TOK * 4);
  unsigned short* xb = (unsigned short*)(ws + 4096 + (size_t)NE * N_TOK * 8);
  unsigned short* Wb = (unsigned short*)(ws + 4096 + (size_t)NE * N_TOK * 8 +
                                         (size_t)N_TOK * D_IN * 2);

  hipMemsetAsync(counts, 0, NE * sizeof(int), stream);
  hipMemsetAsync(out, 0, (size_t)out_size * sizeof(float), stream);

  cast_w_kernel<<<NE * D_OUT * D_IN / 1024, 256, 0, stream>>>(W, Wb);
  gate_kernel<<<N_TOK / 64, 256, 0, stream>>>(x, Wg, bg, xb, counts, bids, bw);
  moe_gemm_kernel<<<NE * 256 * 8, 256, 0, stream>>>(xb, Wb, b, counts, bids, bw, out);
}

// Round 2
// 592.486 us; speedup vs baseline: 1.0434x; 1.0434x over previous
//
#include <hip/hip_runtime.h>
#include <hip/hip_bf16.h>
#include <cstdint>
#include <cstddef>

#define N_TOK   32768
#define D_IN    1024
#define D_OUT   1024
#define NE      8

typedef __attribute__((ext_vector_type(4))) float floatx4;
typedef __attribute__((ext_vector_type(8))) short bf16x8;

__device__ __forceinline__ unsigned short f2bf(float f) {
  union { float f; unsigned int u; } v; v.f = f;
  unsigned int u = v.u + 0x7fffu + ((v.u >> 16) & 1u);   // RNE
  return (unsigned short)(u >> 16);
}

// async global->LDS, 16B per lane; LDS dest is wave-uniform base + lane*16
__device__ __forceinline__ void gload_lds16(const void* g, void* l) {
  __builtin_amdgcn_global_load_lds(
      (const __attribute__((address_space(1))) unsigned int*)g,
      (__attribute__((address_space(3))) unsigned int*)l, 16, 0, 0);
}

// ---------------- fused prep: gate (+x cast) | W cast | out zero ----------------
// blocks [0,512): gating, 64 tokens each
// blocks [512,1024): W fp32->bf16, 16 float4/thread
// blocks [1024,3072): zero d_out, 16 float4/thread
__global__ __launch_bounds__(256) void prep_kernel(
    const float* __restrict__ x,
    const float* __restrict__ Wg,
    const float* __restrict__ bg,
    const float* __restrict__ W,
    unsigned short* __restrict__ xb,
    unsigned short* __restrict__ Wb,
    int* __restrict__ counts,
    int* __restrict__ bids,
    float* __restrict__ bw,
    float* __restrict__ out)
{
  __shared__ float wg_lds[NE * D_IN];   // 32 KB
  __shared__ int lcnt[NE];
  __shared__ int basee[NE];
  __shared__ int   tok_e[64][2];
  __shared__ int   tok_s[64][2];
  __shared__ float tok_w[64][2];

  const int blk = blockIdx.x;
  const int tid = threadIdx.x;

  if (blk >= 1024) {                 // ---- zero out ----
    float4* o4 = (float4*)out;
    const int base = (blk - 1024) * 4096;
#pragma unroll
    for (int i = 0; i < 16; ++i)
      o4[base + i * 256 + tid] = (float4){0.f, 0.f, 0.f, 0.f};
    return;
  }
  if (blk >= 512) {                  // ---- cast W ----
    const float4* s = (const float4*)W;
    const int base = (blk - 512) * 4096;
#pragma unroll
    for (int i = 0; i < 16; ++i) {
      int idx = base + i * 256 + tid;
      float4 v = s[idx];
      ushort4 h;
      h.x = f2bf(v.x); h.y = f2bf(v.y); h.z = f2bf(v.z); h.w = f2bf(v.w);
      ((ushort4*)Wb)[idx] = h;
    }
    return;
  }

  // ---- gating ----
  {
    const float4* s = (const float4*)Wg;
    float4* d = (float4*)wg_lds;
    for (int i = tid; i < NE * D_IN / 4; i += 256) d[i] = s[i];
  }
  if (tid < NE) lcnt[tid] = 0;
  __syncthreads();

  const int wave = tid >> 6, lane = tid & 63;
  const float4* x4 = (const float4*)x;
  const float4* w4 = (const float4*)wg_lds;

  for (int t = 0; t < 16; ++t) {
    const int lt = wave * 16 + t;
    const int n  = blk * 64 + lt;
    float4 xv[4];
    float acc[NE];
#pragma unroll
    for (int e = 0; e < NE; ++e) acc[e] = 0.f;
#pragma unroll
    for (int j = 0; j < 4; ++j) {
      xv[j] = x4[(size_t)n * 256 + j * 64 + lane];
#pragma unroll
      for (int e = 0; e < NE; ++e) {
        float4 w = w4[e * 256 + j * 64 + lane];
        acc[e] += xv[j].x * w.x + xv[j].y * w.y + xv[j].z * w.z + xv[j].w * w.w;
      }
    }
#pragma unroll
    for (int j = 0; j < 4; ++j) {
      ushort4 h;
      h.x = f2bf(xv[j].x); h.y = f2bf(xv[j].y);
      h.z = f2bf(xv[j].z); h.w = f2bf(xv[j].w);
      ((ushort4*)xb)[(size_t)n * 256 + j * 64 + lane] = h;
    }
#pragma unroll
    for (int e = 0; e < NE; ++e)
#pragma unroll
      for (int s = 32; s > 0; s >>= 1)
        acc[e] += __shfl_xor(acc[e], s, 64);

    if (lane == 0) {
      float sc[NE];
#pragma unroll
      for (int e = 0; e < NE; ++e) sc[e] = acc[e] + bg[e];
      float m = sc[0];
#pragma unroll
      for (int e = 1; e < NE; ++e) m = fmaxf(m, sc[e]);
      float p[NE], den = 0.f;
#pragma unroll
      for (int e = 0; e < NE; ++e) { p[e] = __expf(sc[e] - m); den += p[e]; }
      int e1 = 0;
#pragma unroll
      for (int e = 1; e < NE; ++e) if (sc[e] > sc[e1]) e1 = e;   // first-index tie-break
      int e2 = (e1 == 0) ? 1 : 0;
#pragma unroll
      for (int e = 0; e < NE; ++e) if (e != e1 && sc[e] > sc[e2]) e2 = e;
      float inv = 1.f / den;
      tok_e[lt][0] = e1; tok_w[lt][0] = p[e1] * inv; tok_s[lt][0] = atomicAdd(&lcnt[e1], 1);
      tok_e[lt][1] = e2; tok_w[lt][1] = p[e2] * inv; tok_s[lt][1] = atomicAdd(&lcnt[e2], 1);
    }
  }
  __syncthreads();
  if (tid < NE) basee[tid] = atomicAdd(&counts[tid], lcnt[tid]);
  __syncthreads();
  if (tid < 128) {
    int lt = tid >> 1, kk = tid & 1;
    int e = tok_e[lt][kk];
    int slot = basee[e] + tok_s[lt][kk];
    bids[e * N_TOK + slot] = blk * 64 + lt;
    bw[e * N_TOK + slot]   = tok_w[lt][kk];
  }
}

// ---------------- grouped gathered GEMM ----------------
// bid = mt*64 + nt*8 + e : e = XCD id (dispatch round-robins across 8 XCDs),
// so expert e's 2MB bf16 W lives in XCD e's 4MB L2; the 8 nt-siblings of an
// A-tile are dispatch-adjacent on the same XCD for A L2 reuse.
__global__ __launch_bounds__(256) void moe_gemm_kernel(
    const unsigned short* __restrict__ xb,    // [N_TOK, 1024] bf16
    const unsigned short* __restrict__ Wb,    // [8, 1024, 1024] bf16
    const float* __restrict__ bias,           // [8, 1024] fp32
    const int* __restrict__ counts,
    const int* __restrict__ bids,
    const float* __restrict__ bw,
    float* __restrict__ out)                  // [N_TOK, 1024] fp32, pre-zeroed
{
  const int bid = blockIdx.x;
  const int e   = bid & 7;
  const int nt  = (bid >> 3) & 7;
  const int mt  = bid >> 6;
  const int cnt = counts[e];
  const int row0 = mt << 7;
  if (row0 >= cnt) return;
  const int rows = min(128, cnt - row0);

  __shared__ alignas(16) unsigned short Ald[128 * 32];  // 8 KB
  __shared__ alignas(16) unsigned short Bld[128 * 32];  // 8 KB
  __shared__ int   ids[128];
  __shared__ float wts[128];

  const int tid = threadIdx.x;
  if (tid < 128) {
    int src = (tid < rows) ? tid : 0;                   // clamp tail rows to a valid id
    ids[tid] = bids[e * N_TOK + row0 + src];
    wts[tid] = (tid < rows) ? bw[e * N_TOK + row0 + tid] : 0.f;
  }
  __syncthreads();

  const int wave = tid >> 6;
  const int lane = tid & 63;
  const int wm = wave >> 1, wn = wave & 1;

  const int srow = lane >> 2;
  const int koff = (lane & 3) * 8;                      // bf16 elements
  const int seg  = wave * 32;
  const long a_r0 = (long)ids[seg + srow] * D_IN;
  const long a_r1 = (long)ids[seg + 16 + srow] * D_IN;
  const unsigned short* wbe = Wb + (size_t)e * D_OUT * D_IN;
  const long b_r0 = (long)(nt * 128 + seg + srow) * D_IN;
  const long b_r1 = (long)(nt * 128 + seg + 16 + srow) * D_IN;
  unsigned short* aL0 = &Ald[seg * 32];
  unsigned short* aL1 = &Ald[(seg + 16) * 32];
  unsigned short* bL0 = &Bld[seg * 32];
  unsigned short* bL1 = &Bld[(seg + 16) * 32];

  const int m16  = lane & 15;
  const int quad = lane >> 4;

  floatx4 acc[4][4];
#pragma unroll
  for (int i = 0; i < 4; ++i)
#pragma unroll
    for (int j = 0; j < 4; ++j) acc[i][j] = (floatx4){0.f, 0.f, 0.f, 0.f};

  for (int k0 = 0; k0 < D_IN; k0 += 32) {
    gload_lds16(xb + a_r0 + k0 + koff, aL0);
    gload_lds16(xb + a_r1 + k0 + koff, aL1);
    gload_lds16(wbe + b_r0 + k0 + koff, bL0);
    gload_lds16(wbe + b_r1 + k0 + koff, bL1);
    __syncthreads();

    bf16x8 af[4], bf[4];
#pragma unroll
    for (int i = 0; i < 4; ++i)
      af[i] = *(const bf16x8*)&Ald[(wm * 64 + i * 16 + m16) * 32 + quad * 8];
#pragma unroll
    for (int j = 0; j < 4; ++j)
      bf[j] = *(const bf16x8*)&Bld[(wn * 64 + j * 16 + m16) * 32 + quad * 8];
#pragma unroll
    for (int i = 0; i < 4; ++i)
#pragma unroll
      for (int j = 0; j < 4; ++j)
        acc[i][j] = __builtin_amdgcn_mfma_f32_16x16x32_bf16(af[i], bf[j], acc[i][j], 0, 0, 0);
    __syncthreads();
  }

  // epilogue: out[token, col] += w * (acc + bias[col]); C/D map: col=lane&15, row=quad*4+reg
  float bv[4];
  int col[4];
#pragma unroll
  for (int j = 0; j < 4; ++j) {
    col[j] = nt * 128 + wn * 64 + j * 16 + m16;
    bv[j] = bias[e * D_OUT + col[j]];
  }
#pragma unroll
  for (int i = 0; i < 4; ++i) {
#pragma unroll
    for (int r = 0; r < 4; ++r) {
      int rl = wm * 64 + i * 16 + quad * 4 + r;
      if (rl < rows) {
        float w = wts[rl];
        float* orow = out + (size_t)ids[rl] * D_OUT;
#pragma unroll
        for (int j = 0; j < 4; ++j)
          atomicAdd(&orow[col[j]], w * (acc[i][j][r] + bv[j]));
      }
    }
  }
}

extern "C" void kernel_launch(void* const* d_in, const int* in_sizes, int n_in,
                              void* d_out, int out_size, void* d_ws, size_t ws_size,
                              hipStream_t stream) {
  const float* x  = (const float*)d_in[0];
  const float* Wg = (const float*)d_in[1];
  const float* bg = (const float*)d_in[2];
  const float* W  = (const float*)d_in[3];
  const float* b  = (const float*)d_in[4];
  float* out = (float*)d_out;

  // workspace layout: counts | bids(1MB) | bw(1MB) | xb(64MB) | Wb(16MB)
  char* ws = (char*)d_ws;
  int*   counts = (int*)ws;
  int*   bids   = (int*)(ws + 4096);
  float* bw     = (float*)(ws + 4096 + (size_t)NE * N_TOK * 4);
  unsigned short* xb = (unsigned short*)(ws + 4096 + (size_t)NE * N_TOK * 8);
  unsigned short* Wb = (unsigned short*)(ws + 4096 + (size_t)NE * N_TOK * 8 +
                                         (size_t)N_TOK * D_IN * 2);

  hipMemsetAsync(counts, 0, NE * sizeof(int), stream);
  prep_kernel<<<3072, 256, 0, stream>>>(x, Wg, bg, W, xb, Wb, counts, bids, bw, out);
  moe_gemm_kernel<<<NE * 256 * 8, 256, 0, stream>>>(xb, Wb, b, counts, bids, bw, out);
}